// Round 4
// baseline (1807.967 us; speedup 1.0000x reference)
//
#include <hip/hip_runtime.h>

// z_e: [B=64, D=64, H=64, W=64] fp32 ; embeddings: [K=512, D=64] fp32
// out: z_q_st [64,64,64,64] fp32 ++ loss (1 fp32)
constexpr int Dc  = 64;
constexpr int Kc  = 512;
constexpr int HWc = 4096;
constexpr int Nc  = 64 * HWc;                    // 262144 points
constexpr float INV_ELEMS = 1.0f / 16777216.0f;  // 1 / (B*D*H*W)

// 32 dims per thread (D split across a lane pair)
#define H32(M) M(0)M(1)M(2)M(3)M(4)M(5)M(6)M(7)M(8)M(9)M(10)M(11)M(12)M(13)M(14)M(15) \
               M(16)M(17)M(18)M(19)M(20)M(21)M(22)M(23)M(24)M(25)M(26)M(27)M(28)M(29)M(30)M(31)

// ---- kernel 1: per-code squared norms ------------------------------------
__global__ __launch_bounds__(256) void vq_enorm(const float* __restrict__ emb,
                                                float* __restrict__ enorm2) {
    int k = blockIdx.x * blockDim.x + threadIdx.x;   // 0..511
    const float4* e = reinterpret_cast<const float4*>(emb + k * Dc);
    float s0 = 0.f, s1 = 0.f, s2 = 0.f, s3 = 0.f;
#pragma unroll
    for (int i = 0; i < Dc / 4; ++i) {
        float4 v = e[i];
        s0 = fmaf(v.x, v.x, s0);
        s1 = fmaf(v.y, v.y, s1);
        s2 = fmaf(v.z, v.z, s2);
        s3 = fmaf(v.w, v.w, s3);
    }
    enorm2[k] = (s0 + s1) + (s2 + s3);
}

// ---- kernel 2: main VQ — 2 threads per point (D-half split) ---------------
// 32 z-regs/thread -> fits the 64-VGPR bucket -> 8 waves/SIMD.
// Embeddings via per-lane float4 VMEM loads (L1/L2-hot 128 KB table), not the
// scalar pipe: VMEM has deep outstanding-miss capacity; s_load/K$ was the
// stall in R1-R3 (43% VALUBusy at 4 lockstep waves/SIMD).
__global__ __launch_bounds__(256)
__attribute__((amdgpu_waves_per_eu(6, 8)))
void vq_main(const float* __restrict__ z_e,
             const float* __restrict__ emb,
             const float* __restrict__ enorm2,
             float* __restrict__ out,
             float* __restrict__ acc) {
    const int i  = blockIdx.x * blockDim.x + threadIdx.x;  // 0 .. 2N-1
    const int p  = i >> 1;          // point id
    const int h  = i & 1;           // D-half: dims [32h, 32h+32)
    const int b  = p >> 12;
    const int hw = p & 4095;

    const float* zp = z_e + (size_t)b * (Dc * HWc) + (size_t)(32 * h) * HWc + hw;
#define ZDECL(j) float z##j = zp[(size_t)(j) * HWc];
    H32(ZDECL)
#undef ZDECL

    const float* ebase = emb + 32 * h;
    float best = 3.4e38f;
    int   bidx = 0;
#pragma unroll 1
    for (int k = 0; k < Kc; ++k) {
        const float4* ek = reinterpret_cast<const float4*>(ebase + k * Dc);
        float4 e0 = ek[0], e1 = ek[1], e2 = ek[2], e3 = ek[3];
        float4 e4 = ek[4], e5 = ek[5], e6 = ek[6], e7 = ek[7];
        float s0 = 0.f, s1 = 0.f, s2 = 0.f, s3 = 0.f;
        s0 = fmaf(e0.x, z0,  s0); s1 = fmaf(e0.y, z1,  s1); s2 = fmaf(e0.z, z2,  s2); s3 = fmaf(e0.w, z3,  s3);
        s0 = fmaf(e1.x, z4,  s0); s1 = fmaf(e1.y, z5,  s1); s2 = fmaf(e1.z, z6,  s2); s3 = fmaf(e1.w, z7,  s3);
        s0 = fmaf(e2.x, z8,  s0); s1 = fmaf(e2.y, z9,  s1); s2 = fmaf(e2.z, z10, s2); s3 = fmaf(e2.w, z11, s3);
        s0 = fmaf(e3.x, z12, s0); s1 = fmaf(e3.y, z13, s1); s2 = fmaf(e3.z, z14, s2); s3 = fmaf(e3.w, z15, s3);
        s0 = fmaf(e4.x, z16, s0); s1 = fmaf(e4.y, z17, s1); s2 = fmaf(e4.z, z18, s2); s3 = fmaf(e4.w, z19, s3);
        s0 = fmaf(e5.x, z20, s0); s1 = fmaf(e5.y, z21, s1); s2 = fmaf(e5.z, z22, s2); s3 = fmaf(e5.w, z23, s3);
        s0 = fmaf(e6.x, z24, s0); s1 = fmaf(e6.y, z25, s1); s2 = fmaf(e6.z, z26, s2); s3 = fmaf(e6.w, z27, s3);
        s0 = fmaf(e7.x, z28, s0); s1 = fmaf(e7.y, z29, s1); s2 = fmaf(e7.z, z30, s2); s3 = fmaf(e7.w, z31, s3);
        float pd  = (s0 + s1) + (s2 + s3);          // partial dot (this half)
        float od  = __shfl_xor(pd, 1, 64);          // partner half's partial
        float dot = pd + od;                        // commutative -> bit-identical in both lanes
        float dist = fmaf(-2.0f, dot, enorm2[k]);   // ||z||^2 const: argmin-safe
        bool  lt   = dist < best;                   // strict <: first-occurrence
        bidx = lt ? k : bidx;
        best = lt ? dist : best;
    }

    // epilogue: gather winning code (this half), write z_q, squared error
    const float* ep = emb + bidx * Dc + 32 * h;     // divergent gather, L1/L2-hot
    float* op = out + (size_t)b * (Dc * HWc) + (size_t)(32 * h) * HWc + hw;
    float lsum = 0.f;
#define EPI(j) { float e = ep[j]; op[(size_t)(j) * HWc] = e; \
                 float f = e - z##j; lsum = fmaf(f, f, lsum); }
    H32(EPI)
#undef EPI

    // block reduction -> single atomic per block
    float v = lsum;
#pragma unroll
    for (int off = 32; off > 0; off >>= 1) v += __shfl_down(v, off);
    __shared__ float red[4];
    const int lane = threadIdx.x & 63;
    const int wid  = threadIdx.x >> 6;
    if (lane == 0) red[wid] = v;
    __syncthreads();
    if (threadIdx.x == 0) {
        float bs = (red[0] + red[1]) + (red[2] + red[3]);
        atomicAdd(acc, bs);
    }
}

// ---- kernel 3: finalize loss ----------------------------------------------
__global__ void vq_finalize(const float* __restrict__ acc, float* __restrict__ out_loss) {
    out_loss[0] = 1.25f * (acc[0] * INV_ELEMS);
}

extern "C" void kernel_launch(void* const* d_in, const int* in_sizes, int n_in,
                              void* d_out, int out_size, void* d_ws, size_t ws_size,
                              hipStream_t stream) {
    const float* z_e = (const float*)d_in[0];
    const float* emb = (const float*)d_in[1];
    float* out = (float*)d_out;

    float* acc    = (float*)d_ws;                 // 4 B accumulator
    float* enorm2 = (float*)((char*)d_ws + 256);  // 512 floats

    hipMemsetAsync(acc, 0, sizeof(float), stream);
    vq_enorm<<<Kc / 256, 256, 0, stream>>>(emb, enorm2);
    vq_main<<<(2 * Nc) / 256, 256, 0, stream>>>(z_e, emb, enorm2, out, acc);
    vq_finalize<<<1, 1, 0, stream>>>(acc, out + (size_t)Nc * Dc);
}

// Round 5
// 387.074 us; speedup vs baseline: 4.6709x; 4.6709x over previous
//
#include <hip/hip_runtime.h>

// z_e: [B=64, D=64, H=64, W=64] fp32 ; embeddings: [K=512, D=64] fp32
// out: z_q_st [64,64,64,64] fp32 ++ loss (1 fp32)
constexpr int Dc  = 64;
constexpr int Kc  = 512;
constexpr int HWc = 4096;
constexpr int Nc  = 64 * HWc;                    // 262144 points
constexpr int PHASE_CODES = 256;                 // codes per 64KB LDS phase
constexpr float INV_ELEMS = 1.0f / 16777216.0f;  // 1 / (B*D*H*W)

#define G0(M) M(0)M(1)M(2)M(3)M(4)M(5)M(6)M(7)M(8)M(9)M(10)M(11)M(12)M(13)M(14)M(15)
#define G1(M) M(16)M(17)M(18)M(19)M(20)M(21)M(22)M(23)M(24)M(25)M(26)M(27)M(28)M(29)M(30)M(31)
#define G2(M) M(32)M(33)M(34)M(35)M(36)M(37)M(38)M(39)M(40)M(41)M(42)M(43)M(44)M(45)M(46)M(47)
#define G3(M) M(48)M(49)M(50)M(51)M(52)M(53)M(54)M(55)M(56)M(57)M(58)M(59)M(60)M(61)M(62)M(63)
#define ALLD(M) G0(M) G1(M) G2(M) G3(M)

// ---- kernel 1: per-code squared norms ------------------------------------
__global__ __launch_bounds__(256) void vq_enorm(const float* __restrict__ emb,
                                                float* __restrict__ enorm2) {
    int k = blockIdx.x * blockDim.x + threadIdx.x;   // 0..511
    const float4* e = reinterpret_cast<const float4*>(emb + k * Dc);
    float s0 = 0.f, s1 = 0.f, s2 = 0.f, s3 = 0.f;
#pragma unroll
    for (int i = 0; i < Dc / 4; ++i) {
        float4 v = e[i];
        s0 = fmaf(v.x, v.x, s0);
        s1 = fmaf(v.y, v.y, s1);
        s2 = fmaf(v.z, v.z, s2);
        s3 = fmaf(v.w, v.w, s3);
    }
    enorm2[k] = (s0 + s1) + (s2 + s3);
}

// ---- kernel 2: main VQ ----------------------------------------------------
// One thread per point, z[64] in regs (VGPR+AGPR, unified file — R3 showed
// this costs nothing). Codebook staged in LDS (two 64KB phases); k-loop reads
// e_k via wave-uniform ds_read_b128 = broadcast, fixed latency, no K$ misses.
// That replaces the scalar-pipe L2-miss stall that pinned R1-R3 at 43% VALUBusy.
__global__ __launch_bounds__(1024)
__attribute__((amdgpu_waves_per_eu(4, 4)))
void vq_main(const float* __restrict__ z_e,
             const float* __restrict__ emb,
             const float* __restrict__ enorm2,
             float* __restrict__ out,
             float* __restrict__ acc) {
    extern __shared__ float4 elds[];                 // 4096 float4 = 64 KB
    const int tid = threadIdx.x;
    const int p   = blockIdx.x * 1024 + tid;         // point id
    const int b   = p >> 12;
    const int hw  = p & 4095;

    const float* zp = z_e + (size_t)b * (Dc * HWc) + hw;
#define ZDECL(i) float z##i = zp[(size_t)(i) * HWc];
    ALLD(ZDECL)
#undef ZDECL

    float best = 3.4e38f;
    int   bidx = 0;

#pragma unroll 1
    for (int ph = 0; ph < Kc / PHASE_CODES; ++ph) {
        __syncthreads();                             // prior phase fully read
        const float4* src = reinterpret_cast<const float4*>(emb + ph * PHASE_CODES * Dc);
#pragma unroll
        for (int j = 0; j < 4; ++j)                  // 64KB / 1024 thr = 4 float4 each
            elds[tid + j * 1024] = src[tid + j * 1024];
        __syncthreads();

#pragma unroll 1
        for (int kk = 0; kk < PHASE_CODES; ++kk) {
            const float4* ef = elds + kk * (Dc / 4); // wave-uniform -> broadcast
            float s0 = 0.f, s1 = 0.f, s2 = 0.f, s3 = 0.f;
#define FMA4(q, a, bb, c, d) { float4 e = ef[q]; \
            s0 = fmaf(e.x, z##a, s0); s1 = fmaf(e.y, z##bb, s1); \
            s2 = fmaf(e.z, z##c, s2); s3 = fmaf(e.w, z##d, s3); }
            FMA4(0,  0,  1,  2,  3)  FMA4(1,  4,  5,  6,  7)
            FMA4(2,  8,  9, 10, 11)  FMA4(3, 12, 13, 14, 15)
            FMA4(4, 16, 17, 18, 19)  FMA4(5, 20, 21, 22, 23)
            FMA4(6, 24, 25, 26, 27)  FMA4(7, 28, 29, 30, 31)
            FMA4(8, 32, 33, 34, 35)  FMA4(9, 36, 37, 38, 39)
            FMA4(10,40, 41, 42, 43)  FMA4(11,44, 45, 46, 47)
            FMA4(12,48, 49, 50, 51)  FMA4(13,52, 53, 54, 55)
            FMA4(14,56, 57, 58, 59)  FMA4(15,60, 61, 62, 63)
#undef FMA4
            const int k = ph * PHASE_CODES + kk;
            float dot  = (s0 + s1) + (s2 + s3);
            float dist = fmaf(-2.0f, dot, enorm2[k]);  // ||z||^2 const: argmin-safe
            bool  lt   = dist < best;                  // strict <: first-occurrence
            bidx = lt ? k : bidx;
            best = lt ? dist : best;
        }
    }

    // epilogue: gather winning code from GLOBAL (L2-hot; avoids LDS row conflicts)
    const float* ep = emb + bidx * Dc;
    float* op = out + (size_t)b * (Dc * HWc) + hw;
    float lsum = 0.f;
#define EPI(i) { float e = ep[i]; op[(size_t)(i) * HWc] = e; \
                 float f = e - z##i; lsum = fmaf(f, f, lsum); }
    ALLD(EPI)
#undef EPI

    // block reduction -> single atomic per block (16 waves)
    float v = lsum;
#pragma unroll
    for (int off = 32; off > 0; off >>= 1) v += __shfl_down(v, off);
    __shared__ float red[16];
    const int lane = tid & 63;
    const int wid  = tid >> 6;
    if (lane == 0) red[wid] = v;
    __syncthreads();
    if (tid == 0) {
        float bs = 0.f;
#pragma unroll
        for (int w = 0; w < 16; ++w) bs += red[w];
        atomicAdd(acc, bs);
    }
}

// ---- kernel 3: finalize loss ----------------------------------------------
__global__ void vq_finalize(const float* __restrict__ acc, float* __restrict__ out_loss) {
    out_loss[0] = 1.25f * (acc[0] * INV_ELEMS);
}

extern "C" void kernel_launch(void* const* d_in, const int* in_sizes, int n_in,
                              void* d_out, int out_size, void* d_ws, size_t ws_size,
                              hipStream_t stream) {
    const float* z_e = (const float*)d_in[0];
    const float* emb = (const float*)d_in[1];
    float* out = (float*)d_out;

    float* acc    = (float*)d_ws;                 // 4 B accumulator
    float* enorm2 = (float*)((char*)d_ws + 256);  // 512 floats

    hipMemsetAsync(acc, 0, sizeof(float), stream);
    vq_enorm<<<Kc / 256, 256, 0, stream>>>(emb, enorm2);
    vq_main<<<Nc / 1024, 1024, 65536, stream>>>(z_e, emb, enorm2, out, acc);
    vq_finalize<<<1, 1, 0, stream>>>(acc, out + (size_t)Nc * Dc);
}

// Round 6
// 195.257 us; speedup vs baseline: 9.2594x; 1.9824x over previous
//
#include <hip/hip_runtime.h>

// z_e: [B=64, D=64, H=64, W=64] fp32 ; embeddings: [K=512, D=64] fp32
// out: z_q_st [64,64,64,64] fp32 ++ loss (1 fp32)
constexpr int Dc  = 64;
constexpr int Kc  = 512;
constexpr int HWc = 4096;
constexpr int Nc  = 64 * HWc;                    // 262144 points
constexpr float INV_ELEMS = 1.0f / 16777216.0f;
constexpr float FLAG_HALF = 0.00625f;            // W/2, W = 0.0125 dist-window

typedef __attribute__((ext_vector_type(8))) short bf16x8;
typedef __attribute__((ext_vector_type(4))) float f32x4;

static __device__ __forceinline__ short f2bf(float x) {   // RNE fp32->bf16
    unsigned u = __builtin_bit_cast(unsigned, x);
    unsigned r = (u + 0x7FFFu + ((u >> 16) & 1u)) >> 16;
    return (short)r;
}
static __device__ __forceinline__ float bf2f(short h) {
    unsigned u = ((unsigned)(unsigned short)h) << 16;
    return __builtin_bit_cast(float, u);
}

// ---- K1: prep — epos = ||e||^2, split E into bf16 hi/lo --------------------
__global__ __launch_bounds__(256) void vq_prep(const float* __restrict__ emb,
                                               short* __restrict__ Eh,
                                               short* __restrict__ El,
                                               float* __restrict__ epos) {
    int k = blockIdx.x * 256 + threadIdx.x;      // 0..511
    const float* e = emb + (size_t)k * Dc;
    float s0 = 0.f, s1 = 0.f, s2 = 0.f, s3 = 0.f;
#pragma unroll
    for (int d = 0; d < 16; ++d) {
        float v0 = e[d], v1 = e[16 + d], v2 = e[32 + d], v3 = e[48 + d];
        s0 = fmaf(v0, v0, s0); s1 = fmaf(v1, v1, s1);
        s2 = fmaf(v2, v2, s2); s3 = fmaf(v3, v3, s3);
    }
    epos[k] = (s0 + s1) + (s2 + s3);
#pragma unroll
    for (int d = 0; d < Dc; ++d) {
        float v = e[d];
        short h = f2bf(v);
        short l = f2bf(v - bf2f(h));
        Eh[(size_t)k * Dc + d] = h;
        El[(size_t)k * Dc + d] = l;
    }
}

// ---- K2: main — MFMA distances + argmax + flag + z_q + loss ----------------
// Wave handles 64 points (4 point-tiles of 16). A = E (codes x k), B = Z.
// acc init = -epos/2  =>  acc_final = dot - ||e||^2/2; dist = -2*acc => argMAX.
__global__ __launch_bounds__(256)
__attribute__((amdgpu_waves_per_eu(3, 4)))
void vq_main(const float* __restrict__ z_e, const float* __restrict__ emb,
             const short* __restrict__ Eh, const short* __restrict__ El,
             const float* __restrict__ epos, float* __restrict__ out,
             float* __restrict__ acc, unsigned int* __restrict__ flags) {
    const int tid  = threadIdx.x;
    const int wave = tid >> 6, lane = tid & 63;
    const int pbase = (blockIdx.x * 4 + wave) * 64;
    const int b = pbase >> 12, hw0 = pbase & 4095;
    const int p16 = lane & 15, g = lane >> 4;

    const float* zbase = z_e + (size_t)b * (Dc * HWc) + hw0;

    // Z fragments: zh/zl[t][c], element j -> Z[k = c*32 + g*8 + j][pt = t*16+p16]
    bf16x8 zh[4][2], zl[4][2];
#pragma unroll
    for (int t = 0; t < 4; ++t)
#pragma unroll
        for (int c = 0; c < 2; ++c)
#pragma unroll
            for (int j = 0; j < 8; ++j) {
                int d = c * 32 + g * 8 + j;
                float zf = zbase[(size_t)d * HWc + t * 16 + p16];
                short h = f2bf(zf);
                zh[t][c][j] = h;
                zl[t][c][j] = f2bf(zf - bf2f(h));
            }

    float a1[4], a2[4]; int i1[4];
#pragma unroll
    for (int t = 0; t < 4; ++t) { a1[t] = -3.4e38f; a2[t] = -3.4e38f; i1[t] = 0; }

#pragma unroll 1
    for (int kt = 0; kt < Kc / 16; ++kt) {
        // E fragments: row = kt*16 + p16, k-elems at c*32 + g*8
        const short* ehr = Eh + (size_t)(kt * 16 + p16) * Dc + g * 8;
        const short* elr = El + (size_t)(kt * 16 + p16) * Dc + g * 8;
        bf16x8 eh0 = *(const bf16x8*)(ehr);
        bf16x8 eh1 = *(const bf16x8*)(ehr + 32);
        bf16x8 el0 = *(const bf16x8*)(elr);
        bf16x8 el1 = *(const bf16x8*)(elr + 32);
        f32x4 eno = *(const f32x4*)(epos + kt * 16 + g * 4);   // codes g*4+r of tile
        f32x4 cinit = -0.5f * eno;
#pragma unroll
        for (int t = 0; t < 4; ++t) {
            f32x4 c = cinit;
            c = __builtin_amdgcn_mfma_f32_16x16x32_bf16(eh0, zh[t][0], c, 0, 0, 0);
            c = __builtin_amdgcn_mfma_f32_16x16x32_bf16(eh1, zh[t][1], c, 0, 0, 0);
            c = __builtin_amdgcn_mfma_f32_16x16x32_bf16(eh0, zl[t][0], c, 0, 0, 0);
            c = __builtin_amdgcn_mfma_f32_16x16x32_bf16(eh1, zl[t][1], c, 0, 0, 0);
            c = __builtin_amdgcn_mfma_f32_16x16x32_bf16(el0, zh[t][0], c, 0, 0, 0);
            c = __builtin_amdgcn_mfma_f32_16x16x32_bf16(el1, zh[t][1], c, 0, 0, 0);
#pragma unroll
            for (int r = 0; r < 4; ++r) {                      // code = kt*16+g*4+r, ascending
                float s = c[r];
                int code = kt * 16 + g * 4 + r;
                bool gt = s > a1[t];                           // strict: first-occurrence
                float dem = gt ? a1[t] : s;
                a2[t] = fmaxf(dem, a2[t]);
                i1[t] = gt ? code : i1[t];
                a1[t] = gt ? s : a1[t];
            }
        }
    }

    // merge (a1,i1,a2) across the 4 lane-groups (code subsets), per point
#pragma unroll
    for (int off = 16; off <= 32; off <<= 1)
#pragma unroll
        for (int t = 0; t < 4; ++t) {
            float oa1 = __shfl_xor(a1[t], off, 64);
            float oa2 = __shfl_xor(a2[t], off, 64);
            int   oi1 = __shfl_xor(i1[t], off, 64);
            float lo  = fminf(a1[t], oa1);
            a2[t] = fmaxf(fmaxf(a2[t], oa2), lo);
            bool take = (oa1 > a1[t]) || (oa1 == a1[t] && oi1 < i1[t]);
            a1[t] = take ? oa1 : a1[t];
            i1[t] = take ? oi1 : i1[t];
        }

    // flags bitmask (one 32-bit word per 32 points; wave owns 2 words)
    unsigned m[4];
#pragma unroll
    for (int t = 0; t < 4; ++t) {
        bool flg = (a1[t] - a2[t]) <= FLAG_HALF;               // near-tie in approx metric
        m[t] = (unsigned)(__ballot(g == 0 && flg) & 0xFFFFull);
    }
    if (lane == 0) {
        flags[pbase / 32]     = m[0] | (m[1] << 16);
        flags[pbase / 32 + 1] = m[2] | (m[3] << 16);
    }

    // epilogue: gather exact fp32 code rows, write z_q, loss partial
    float lsum = 0.f;
#pragma unroll 1
    for (int t = 0; t < 4; ++t) {
        const float* er  = emb + (size_t)i1[t] * Dc;
        float* op        = out + (size_t)b * (Dc * HWc) + hw0 + t * 16 + p16;
        const float* zp2 = zbase + t * 16 + p16;
#pragma unroll
        for (int dd = 0; dd < 16; ++dd) {
            int d = g * 16 + dd;                               // lane-group covers d-quarter
            float e = er[d];
            op[(size_t)d * HWc] = e;
            float f = e - zp2[(size_t)d * HWc];
            lsum = fmaf(f, f, lsum);
        }
    }
    float v = lsum;
#pragma unroll
    for (int off = 32; off > 0; off >>= 1) v += __shfl_down(v, off);
    if (lane == 0) atomicAdd(acc, v);
}

// ---- K3: exact fp32 fixup for flagged points -------------------------------
__global__ __launch_bounds__(256) void vq_fixup(const float* __restrict__ z_e,
                                                const float* __restrict__ emb,
                                                const float* __restrict__ epos,
                                                const unsigned int* __restrict__ flags,
                                                float* __restrict__ out,
                                                float* __restrict__ acc) {
    const int lane = threadIdx.x & 63;
    const int wid  = (blockIdx.x * 256 + threadIdx.x) >> 6;
    const int nw   = (gridDim.x * 256) >> 6;
    for (int w = wid; w < Nc / 32; w += nw) {
        unsigned f = flags[w];
        while (f) {
            int bit = __ffs(f) - 1; f &= f - 1;
            int p = w * 32 + bit;
            int b = p >> 12, hw = p & 4095;
            const float* zp = z_e + (size_t)b * (Dc * HWc) + hw;
            float z[Dc];
#pragma unroll
            for (int d = 0; d < Dc; ++d) z[d] = zp[(size_t)d * HWc];  // broadcast
            float bd = 3.4e38f; int bi = 0;
#pragma unroll 1
            for (int r = 0; r < 8; ++r) {                      // codes r*64 + lane
                int code = r * 64 + lane;
                const float* er = emb + (size_t)code * Dc;
                float s0 = 0.f, s1 = 0.f, s2 = 0.f, s3 = 0.f;
#pragma unroll
                for (int d = 0; d < 16; ++d) {                 // R1-proven numerics
                    s0 = fmaf(er[d],      z[d],      s0);
                    s1 = fmaf(er[16 + d], z[16 + d], s1);
                    s2 = fmaf(er[32 + d], z[32 + d], s2);
                    s3 = fmaf(er[48 + d], z[48 + d], s3);
                }
                float dot  = (s0 + s1) + (s2 + s3);
                float dist = fmaf(-2.0f, dot, epos[code]);
                if (dist < bd) { bd = dist; bi = code; }       // within-lane ascending
            }
#pragma unroll
            for (int off = 32; off > 0; off >>= 1) {           // cross-lane argmin
                float od = __shfl_xor(bd, off, 64);
                int   oi = __shfl_xor(bi, off, 64);
                bool take = (od < bd) || (od == bd && oi < bi);
                bd = take ? od : bd;
                bi = take ? oi : bi;
            }
            // patch z_q column + loss delta (lane = d)
            float* op = out + (size_t)b * (Dc * HWc) + (size_t)lane * HWc + hw;
            float eo = *op;
            float en = emb[(size_t)bi * Dc + lane];
            float zf = z[0];  // placeholder; need z[lane] -> reload (registers not indexable)
            zf = zp[(size_t)lane * HWc];
            float dn = en - zf, dold = eo - zf;
            float delta = fmaf(dn, dn, -dold * dold);
            *op = en;
#pragma unroll
            for (int off = 32; off > 0; off >>= 1) delta += __shfl_down(delta, off);
            if (lane == 0) atomicAdd(acc, delta);
        }
    }
}

// ---- K4: finalize loss -----------------------------------------------------
__global__ void vq_finalize(const float* __restrict__ acc, float* __restrict__ out_loss) {
    out_loss[0] = 1.25f * (acc[0] * INV_ELEMS);
}

extern "C" void kernel_launch(void* const* d_in, const int* in_sizes, int n_in,
                              void* d_out, int out_size, void* d_ws, size_t ws_size,
                              hipStream_t stream) {
    const float* z_e = (const float*)d_in[0];
    const float* emb = (const float*)d_in[1];
    float* out = (float*)d_out;

    char* ws = (char*)d_ws;
    float*    acc   = (float*)(ws);                 // 4 B
    float*    epos  = (float*)(ws + 256);           // 512 f32 = 2 KB
    unsigned* flags = (unsigned*)(ws + 4096);       // N/32 u32 = 32 KB
    short*    Eh    = (short*)(ws + 65536);         // 64 KB
    short*    El    = (short*)(ws + 131072);        // 64 KB

    hipMemsetAsync(acc, 0, sizeof(float), stream);
    vq_prep<<<2, 256, 0, stream>>>(emb, Eh, El, epos);
    vq_main<<<Nc / 256, 256, 0, stream>>>(z_e, emb, Eh, El, epos, out, acc, flags);
    vq_fixup<<<256, 256, 0, stream>>>(z_e, emb, epos, flags, out, acc);
    vq_finalize<<<1, 1, 0, stream>>>(acc, out + (size_t)Nc * Dc);
}

// Round 7
// 194.369 us; speedup vs baseline: 9.3017x; 1.0046x over previous
//
#include <hip/hip_runtime.h>

// z_e: [B=64, D=64, H=64, W=64] fp32 ; embeddings: [K=512, D=64] fp32
// out: z_q_st [64,64,64,64] fp32 ++ loss (1 fp32)
constexpr int Dc  = 64;
constexpr int Kc  = 512;
constexpr int HWc = 4096;
constexpr int Nc  = 64 * HWc;                    // 262144 points
constexpr float INV_ELEMS = 1.0f / 16777216.0f;
constexpr float FLAG_HALF = 0.00625f;            // W/2, W = 0.0125 dist-window

typedef __attribute__((ext_vector_type(8))) short bf16x8;
typedef __attribute__((ext_vector_type(4))) float f32x4;

static __device__ __forceinline__ short f2bf(float x) {   // RNE fp32->bf16
    unsigned u = __builtin_bit_cast(unsigned, x);
    unsigned r = (u + 0x7FFFu + ((u >> 16) & 1u)) >> 16;
    return (short)r;
}
static __device__ __forceinline__ float bf2f(short h) {
    unsigned u = ((unsigned)(unsigned short)h) << 16;
    return __builtin_bit_cast(float, u);
}

// ---- K1a: eposneg[k] = -0.5 * ||e_k||^2 ------------------------------------
__global__ __launch_bounds__(256) void vq_eposneg(const float* __restrict__ emb,
                                                  float* __restrict__ eposneg) {
    int k = blockIdx.x * 256 + threadIdx.x;      // 0..511
    const float* e = emb + (size_t)k * Dc;
    float s0 = 0.f, s1 = 0.f, s2 = 0.f, s3 = 0.f;
#pragma unroll
    for (int d = 0; d < 16; ++d) {
        float v0 = e[d], v1 = e[16 + d], v2 = e[32 + d], v3 = e[48 + d];
        s0 = fmaf(v0, v0, s0); s1 = fmaf(v1, v1, s1);
        s2 = fmaf(v2, v2, s2); s3 = fmaf(v3, v3, s3);
    }
    eposneg[k] = -0.5f * ((s0 + s1) + (s2 + s3));
}

// ---- K1b: pack E into fragment-major bf16 hi/lo stream (128 KB) ------------
// 16B chunk q: kt=q>>8, lo=(q>>7)&1, c=(q>>6)&1, lane=q&63 (p16=lane&15,
// g=lane>>4); content = {hi|lo} bf16 of emb[kt*16+p16][c*32+g*8 .. +8).
// This is EXACTLY the per-lane fragment vq_main's wave reads -> lane-linear LDS.
__global__ __launch_bounds__(256) void vq_packE(const float* __restrict__ emb,
                                                short* __restrict__ EF) {
    int q  = blockIdx.x * 256 + threadIdx.x;     // 0..8191
    int kt = q >> 8, lo = (q >> 7) & 1, c = (q >> 6) & 1, lane = q & 63;
    int code = kt * 16 + (lane & 15);
    int d0   = c * 32 + (lane >> 4) * 8;
    const float* e = emb + (size_t)code * Dc + d0;
    bf16x8 v;
#pragma unroll
    for (int j = 0; j < 8; ++j) {
        float x = e[j];
        short h = f2bf(x);
        v[j] = lo ? f2bf(x - bf2f(h)) : h;
    }
    *reinterpret_cast<bf16x8*>(EF + (size_t)q * 8) = v;
}

// ---- K2: main — LDS-staged E, MFMA distances, argmax+flag, z_q + loss ------
// 1024 threads = 16 waves, 1 block/CU (128 KB LDS), 4 waves/SIMD.
// Wave handles 32 points (2 tiles of 16). Math identical to R6 (verified):
// c init = -||e||^2/2, 3-term split-bf16 dot, argMAX of s = dot - ||e||^2/2.
__global__ __launch_bounds__(1024)
void vq_main(const float* __restrict__ z_e, const float* __restrict__ emb,
             const short* __restrict__ EF, const float* __restrict__ eposneg,
             float* __restrict__ out, float* __restrict__ acc,
             unsigned int* __restrict__ flags) {
    extern __shared__ __align__(16) char smem[];         // 128 KB
    const int tid = threadIdx.x;

    // stage EF -> LDS, linear 16B chunks, fully coalesced
    {
        const bf16x8* src = reinterpret_cast<const bf16x8*>(EF);
        bf16x8*       dst = reinterpret_cast<bf16x8*>(smem);
#pragma unroll
        for (int i = 0; i < 8; ++i) dst[tid + i * 1024] = src[tid + i * 1024];
    }
    __syncthreads();

    const int wave = tid >> 6, lane = tid & 63;
    const int p16 = lane & 15, g = lane >> 4;
    const int pbase = blockIdx.x * 512 + wave * 32;      // 32 points per wave
    const int b = pbase >> 12, hw0 = pbase & 4095;
    const float* zbase = z_e + (size_t)b * (Dc * HWc) + hw0;

    // Z fragments: element j -> Z[d = c*32+g*8+j][point = t*16+p16]
    bf16x8 zh[2][2], zl[2][2];
#pragma unroll
    for (int t = 0; t < 2; ++t)
#pragma unroll
        for (int c = 0; c < 2; ++c)
#pragma unroll
            for (int j = 0; j < 8; ++j) {
                int d = c * 32 + g * 8 + j;
                float zf = zbase[(size_t)d * HWc + t * 16 + p16];
                short h = f2bf(zf);
                zh[t][c][j] = h;
                zl[t][c][j] = f2bf(zf - bf2f(h));
            }

    float a1[2], a2[2]; int i1[2];
#pragma unroll
    for (int t = 0; t < 2; ++t) { a1[t] = -3.4e38f; a2[t] = -3.4e38f; i1[t] = 0; }

    f32x4 en = *reinterpret_cast<const f32x4*>(eposneg + g * 4);   // kt = 0
#pragma unroll 1
    for (int kt = 0; kt < Kc / 16; ++kt) {
        // prefetch next kt's -||e||^2/2 (clamped index; last value unused)
        f32x4 en_next = *reinterpret_cast<const f32x4*>(
            eposneg + ((kt + 1) & 31) * 16 + g * 4);
        const char* ebase = smem + kt * 4096 + lane * 16;          // lane-linear
        bf16x8 eh0 = *reinterpret_cast<const bf16x8*>(ebase);
        bf16x8 eh1 = *reinterpret_cast<const bf16x8*>(ebase + 1024);
        bf16x8 el0 = *reinterpret_cast<const bf16x8*>(ebase + 2048);
        bf16x8 el1 = *reinterpret_cast<const bf16x8*>(ebase + 3072);
#pragma unroll
        for (int t = 0; t < 2; ++t) {
            f32x4 c = en;
            c = __builtin_amdgcn_mfma_f32_16x16x32_bf16(eh0, zh[t][0], c, 0, 0, 0);
            c = __builtin_amdgcn_mfma_f32_16x16x32_bf16(eh1, zh[t][1], c, 0, 0, 0);
            c = __builtin_amdgcn_mfma_f32_16x16x32_bf16(eh0, zl[t][0], c, 0, 0, 0);
            c = __builtin_amdgcn_mfma_f32_16x16x32_bf16(eh1, zl[t][1], c, 0, 0, 0);
            c = __builtin_amdgcn_mfma_f32_16x16x32_bf16(el0, zh[t][0], c, 0, 0, 0);
            c = __builtin_amdgcn_mfma_f32_16x16x32_bf16(el1, zh[t][1], c, 0, 0, 0);
#pragma unroll
            for (int r = 0; r < 4; ++r) {                // code ascending in r
                float s = c[r];
                int code = kt * 16 + g * 4 + r;
                bool gt = s > a1[t];                     // strict: first-occurrence
                float dem = gt ? a1[t] : s;
                a2[t] = fmaxf(dem, a2[t]);
                i1[t] = gt ? code : i1[t];
                a1[t] = gt ? s : a1[t];
            }
        }
        en = en_next;
    }

    // merge (a1,i1,a2) across the 4 lane-groups (code subsets), per point
#pragma unroll
    for (int off = 16; off <= 32; off <<= 1)
#pragma unroll
        for (int t = 0; t < 2; ++t) {
            float oa1 = __shfl_xor(a1[t], off, 64);
            float oa2 = __shfl_xor(a2[t], off, 64);
            int   oi1 = __shfl_xor(i1[t], off, 64);
            float lo  = fminf(a1[t], oa1);
            a2[t] = fmaxf(fmaxf(a2[t], oa2), lo);
            bool take = (oa1 > a1[t]) || (oa1 == a1[t] && oi1 < i1[t]);
            a1[t] = take ? oa1 : a1[t];
            i1[t] = take ? oi1 : i1[t];
        }

    // flags: one 32-bit word per 32 points (this wave's exact span)
    unsigned m[2];
#pragma unroll
    for (int t = 0; t < 2; ++t) {
        bool flg = (a1[t] - a2[t]) <= FLAG_HALF;         // near-tie in approx metric
        m[t] = (unsigned)(__ballot(g == 0 && flg) & 0xFFFFull);
    }
    if (lane == 0) flags[pbase / 32] = m[0] | (m[1] << 16);

    // epilogue: gather exact fp32 code rows, write z_q, loss from zh+zl
    // (zh+zl reconstructs z to ~2e-5 relative: loss error ~1e-5, negligible)
    float lsum = 0.f;
#pragma unroll
    for (int t = 0; t < 2; ++t) {
        const float* er = emb + (size_t)i1[t] * Dc;
        float* op = out + (size_t)b * (Dc * HWc) + hw0 + t * 16 + p16;
#pragma unroll
        for (int c = 0; c < 2; ++c)
#pragma unroll
            for (int j = 0; j < 8; ++j) {
                int d = c * 32 + g * 8 + j;              // lane's own d-slots
                float e = er[d];
                op[(size_t)d * HWc] = e;
                float zr = bf2f(zh[t][c][j]) + bf2f(zl[t][c][j]);
                float f = e - zr;
                lsum = fmaf(f, f, lsum);
            }
    }
    float v = lsum;
#pragma unroll
    for (int off = 32; off > 0; off >>= 1) v += __shfl_down(v, off);
    if (lane == 0) atomicAdd(acc, v);
}

// ---- K3: exact fp32 fixup for flagged points -------------------------------
__global__ __launch_bounds__(256) void vq_fixup(const float* __restrict__ z_e,
                                                const float* __restrict__ emb,
                                                const float* __restrict__ eposneg,
                                                const unsigned int* __restrict__ flags,
                                                float* __restrict__ out,
                                                float* __restrict__ acc) {
    const int lane = threadIdx.x & 63;
    const int wid  = (blockIdx.x * 256 + threadIdx.x) >> 6;
    const int nw   = (gridDim.x * 256) >> 6;
    for (int w = wid; w < Nc / 32; w += nw) {
        unsigned f = flags[w];
        while (f) {
            int bit = __ffs(f) - 1; f &= f - 1;
            int p = w * 32 + bit;
            int b = p >> 12, hw = p & 4095;
            const float* zp = z_e + (size_t)b * (Dc * HWc) + hw;
            float z[Dc];
#pragma unroll
            for (int d = 0; d < Dc; ++d) z[d] = zp[(size_t)d * HWc];  // broadcast
            float bd = 3.4e38f; int bi = 0;
#pragma unroll 1
            for (int r = 0; r < 8; ++r) {                // codes r*64 + lane
                int code = r * 64 + lane;
                const float* er = emb + (size_t)code * Dc;
                float s0 = 0.f, s1 = 0.f, s2 = 0.f, s3 = 0.f;
#pragma unroll
                for (int d = 0; d < 16; ++d) {           // R1-proven numerics
                    s0 = fmaf(er[d],      z[d],      s0);
                    s1 = fmaf(er[16 + d], z[16 + d], s1);
                    s2 = fmaf(er[32 + d], z[32 + d], s2);
                    s3 = fmaf(er[48 + d], z[48 + d], s3);
                }
                float dot  = (s0 + s1) + (s2 + s3);
                float dist = fmaf(-2.0f, dot, -2.0f * eposneg[code]); // +||e||^2
                if (dist < bd) { bd = dist; bi = code; } // within-lane ascending
            }
#pragma unroll
            for (int off = 32; off > 0; off >>= 1) {     // cross-lane argmin
                float od = __shfl_xor(bd, off, 64);
                int   oi = __shfl_xor(bi, off, 64);
                bool take = (od < bd) || (od == bd && oi < bi);
                bd = take ? od : bd;
                bi = take ? oi : bi;
            }
            // patch z_q column + loss delta (lane = d)
            float* op = out + (size_t)b * (Dc * HWc) + (size_t)lane * HWc + hw;
            float eo = *op;
            float en = emb[(size_t)bi * Dc + lane];
            float zf = zp[(size_t)lane * HWc];
            float dn = en - zf, dold = eo - zf;
            float delta = fmaf(dn, dn, -dold * dold);
            *op = en;
#pragma unroll
            for (int off = 32; off > 0; off >>= 1) delta += __shfl_down(delta, off);
            if (lane == 0) atomicAdd(acc, delta);
        }
    }
}

// ---- K4: finalize loss -----------------------------------------------------
__global__ void vq_finalize(const float* __restrict__ acc, float* __restrict__ out_loss) {
    out_loss[0] = 1.25f * (acc[0] * INV_ELEMS);
}

extern "C" void kernel_launch(void* const* d_in, const int* in_sizes, int n_in,
                              void* d_out, int out_size, void* d_ws, size_t ws_size,
                              hipStream_t stream) {
    const float* z_e = (const float*)d_in[0];
    const float* emb = (const float*)d_in[1];
    float* out = (float*)d_out;

    char* ws = (char*)d_ws;
    float*    acc     = (float*)(ws);                 // 4 B
    float*    eposneg = (float*)(ws + 256);           // 512 f32 = 2 KB
    unsigned* flags   = (unsigned*)(ws + 4096);       // N/32 u32 = 32 KB
    short*    EF      = (short*)(ws + 65536);         // 128 KB fragment stream

    // allow 128 KB dynamic LDS (idempotent host-side call; capture-safe)
    hipFuncSetAttribute(reinterpret_cast<const void*>(vq_main),
                        hipFuncAttributeMaxDynamicSharedMemorySize, 131072);

    hipMemsetAsync(acc, 0, sizeof(float), stream);
    vq_eposneg<<<2, 256, 0, stream>>>(emb, eposneg);
    vq_packE<<<32, 256, 0, stream>>>(emb, EF);
    vq_main<<<Nc / 512, 1024, 131072, stream>>>(z_e, emb, EF, eposneg, out, acc, flags);
    vq_fixup<<<256, 256, 0, stream>>>(z_e, emb, eposneg, flags, out, acc);
    vq_finalize<<<1, 1, 0, stream>>>(acc, out + (size_t)Nc * Dc);
}